// Round 1
// baseline (418.458 us; speedup 1.0000x reference)
//
#include <hip/hip_runtime.h>

#define TT 512
#define BB 256
#define NN 128
#define MW 16            // chains per workgroup (comb / fallback)
#define NWG (BB / MW)    // 16
#define G2 8             // fb2 chain-groups (32 chains each)
#define STH 144

// ws layout (bytes)
#define LENS_OFF 256
#define AF_OFF 2048
#define CF_OFF (AF_OFF + BB * NN * 4)
#define BU_OFF (CF_OFF + 1024)
#define CB_OFF (BU_OFF + BB * NN * 4)
#define XQ_OFF (CB_OFF + 1024)
#define XQ_SZ ((size_t)TT * BB * NN * 2)

typedef __attribute__((ext_vector_type(8))) short short8_t;
typedef __attribute__((ext_vector_type(4))) float f32x4;
typedef __attribute__((ext_vector_type(16))) float f32x16;

__device__ __forceinline__ unsigned short f2bf(float f) {
  unsigned u = __float_as_uint(f);
  return (unsigned short)((u + 0x7FFF + ((u >> 16) & 1)) >> 16);  // RNE
}
__device__ __forceinline__ float bf2f(unsigned short h) {
  return __uint_as_float(((unsigned)h) << 16);
}
// storage position p <-> original index:  idx = 32w+16u+c  <->  p = 32w+2c+u
__device__ __forceinline__ int orig_j(int p) {
  return 32 * (p >> 5) + 16 * (p & 1) + ((p >> 1) & 15);
}
__device__ __forceinline__ int pos_p(int j) {  // natural state j -> comb storage p
  return 32 * (j >> 5) + 2 * (j & 15) + ((j >> 4) & 1);
}

#define U4GET(v_, i_) \
  ((i_) == 0 ? (v_).x : (i_) == 1 ? (v_).y : (i_) == 2 ? (v_).z : (v_).w)

// ---------- Phase 1a: X[g][t][...] = exp(emit) bf16, fb2 consumer layout ---
// Per (g,t): 2048 u32.  word w = 8T+2m+rp holds states j0=32T+8m+4h+2rp, j0+1
// (chain = g*32 + (lane&31), h = lane>>5).  u32 addr = (whi*64+lane)*4 + wlo.
__global__ __launch_bounds__(256) void crf_expemit2(
    const float* __restrict__ emit, uint4* __restrict__ Xq) {
  const int wid = blockIdx.x * 4 + (threadIdx.x >> 6);
  const int l = threadIdx.x & 63;
  const int c5 = l & 31, h = l >> 5;
  const int g = wid >> 9;
  const int t = wid & (TT - 1);
  const int b = g * 32 + c5;
  const float* row = emit + ((size_t)t * BB + b) * NN;
  unsigned wd[32];
#pragma unroll
  for (int q = 0; q < 16; ++q) {  // q = 4T+m, chunk at j = 8q+4h
    const float4 f = *(const float4*)(row + 8 * q + 4 * h);
    const float a0 = __expf(f.x), a1 = __expf(f.y);
    const float a2 = __expf(f.z), a3 = __expf(f.w);
    wd[2 * q] = (unsigned)f2bf(a0) | ((unsigned)f2bf(a1) << 16);
    wd[2 * q + 1] = (unsigned)f2bf(a2) | ((unsigned)f2bf(a3) << 16);
  }
  uint4* out = Xq + ((size_t)g * TT + t) * 512 + l;
#pragma unroll
  for (int whi = 0; whi < 8; ++whi)
    out[whi * 64] =
        make_uint4(wd[4 * whi], wd[4 * whi + 1], wd[4 * whi + 2], wd[4 * whi + 3]);
}

// ---------- Phase 1b: gold score + per-chain lengths (unchanged) -----------
__global__ __launch_bounds__(BB) void crf_score_k(
    const float* __restrict__ emit, const int* __restrict__ target,
    const void* __restrict__ maskp, const float* __restrict__ trans,
    const float* __restrict__ strans, const float* __restrict__ etrans,
    float* __restrict__ ws, int* __restrict__ lens) {
  __shared__ float rf[4];
  const int b = threadIdx.x;
  const int t = blockIdx.x;
  const unsigned char* mk8 = (const unsigned char*)maskp;
  const int* mk32 = (const int*)maskp;
  const bool is_u8 = (mk8[1] != 0);

  int m = is_u8 ? (mk8[t * BB + b] != 0) : (mk32[t * BB + b] != 0);
  float v = 0.f;
  if (m) {
    int tg = target[t * BB + b];
    v = emit[((size_t)t * BB + b) * NN + tg];
    v += (t > 0) ? trans[target[(t - 1) * BB + b] * NN + tg] : strans[tg];
    int mn = (t + 1 < TT) ? (is_u8 ? (mk8[(t + 1) * BB + b] != 0)
                                   : (mk32[(t + 1) * BB + b] != 0))
                          : 0;
    if (!mn) {  // prefix-mask edge = last valid step
      v += etrans[tg];
      lens[b] = t + 1;
    }
  }
#pragma unroll
  for (int off = 32; off; off >>= 1) v += __shfl_down(v, off, 64);
  if ((b & 63) == 0) rf[b >> 6] = v;
  __syncthreads();
  if (b == 0) atomicAdd(&ws[1], rf[0] + rf[1] + rf[2] + rf[3]);
}

// ---------- Phase 2 helpers ------------------------------------------------
__device__ __forceinline__ void dump_state(const float (&v0a)[4][4][2],
                                           const float (&v1a)[4][4][2],
                                           float* __restrict__ OUT, int b,
                                           int h) {
#pragma unroll
  for (int T = 0; T < 4; ++T)
#pragma unroll
    for (int m = 0; m < 4; ++m)
#pragma unroll
      for (int rp = 0; rp < 2; ++rp) {
        const int j0 = 32 * T + 8 * m + 4 * h + 2 * rp;
        OUT[b * NN + pos_p(j0)] = v0a[T][m][rp];
        OUT[b * NN + pos_p(j0 + 1)] = v1a[T][m][rp];
      }
}

// cvt f32 pairs -> bf16 words, then permlane32_swap relayout D -> B operand.
// B(kt'=2T+a, j2): fields x=j2_0, y=j2_1, z=j2_2, w=j2_3.
__device__ __forceinline__ void cvtperm(const float (&v0a)[4][4][2],
                                        const float (&v1a)[4][4][2],
                                        uint4 (&Bq)[8]) {
  unsigned W[4][4][2];
#pragma unroll
  for (int T = 0; T < 4; ++T)
#pragma unroll
    for (int m = 0; m < 4; ++m)
#pragma unroll
      for (int rp = 0; rp < 2; ++rp) {
        unsigned wv;
        asm("v_cvt_pk_bf16_f32 %0, %1, %2"
            : "=v"(wv)
            : "v"(v0a[T][m][rp]), "v"(v1a[T][m][rp]));
        W[T][m][rp] = wv;
      }
#pragma unroll
  for (int T = 0; T < 4; ++T)
#pragma unroll
    for (int a = 0; a < 2; ++a) {
      unsigned X0 = W[T][2 * a][0], Y0 = W[T][2 * a + 1][0];
      unsigned X1 = W[T][2 * a][1], Y1 = W[T][2 * a + 1][1];
      asm("v_permlane32_swap_b32 %0, %1" : "+v"(X0), "+v"(Y0));
      asm("v_permlane32_swap_b32 %0, %1" : "+v"(X1), "+v"(Y1));
      Bq[2 * T + a] = make_uint4(X0, X1, Y0, Y1);
    }
}

template <bool BWD>
__device__ __forceinline__ void fb_step(
    int t, bool donorm, bool dfinal, int tpre, int lm1, int c5, int h, int b,
    const uint4* __restrict__ Xg, const short8_t (&eA)[4][8],
    const f32x16& kZ, uint4 (&Bq)[8], uint4 (&xw)[8], int& cloc,
    const float* __restrict__ etrans, float* __restrict__ OUT,
    int* __restrict__ CNT) {
  union U8 { uint4 u; short8_t s; };
  // ---- MFMA: D[128 x 32chains] = E (A-op, regs) x state (B-op) ----
  f32x16 dd[4];
  {
    U8 bc;
    bc.u = Bq[0];
#pragma unroll
    for (int T = 0; T < 4; ++T)
      dd[T] = __builtin_amdgcn_mfma_f32_32x32x16_bf16(eA[T][0], bc.s, kZ, 0, 0, 0);
  }
#pragma unroll
  for (int k = 1; k < 8; ++k) {
    U8 bc;
    bc.u = Bq[k];
#pragma unroll
    for (int T = 0; T < 4; ++T)
      dd[T] =
          __builtin_amdgcn_mfma_f32_32x32x16_bf16(eA[T][k], bc.s, dd[T], 0, 0, 0);
  }
  // ---- snapshot this step's x, issue prefetch for t +/- 2 ----
  uint4 xv[8];
#pragma unroll
  for (int i = 0; i < 8; ++i) xv[i] = xw[i];
  {
    const uint4* src = Xg + (size_t)tpre * 512;
#pragma unroll
    for (int i = 0; i < 8; ++i) xw[i] = src[i * 64];
  }
  // ---- epilogue: v = D * x ----
  float v0a[4][4][2], v1a[4][4][2];
#pragma unroll
  for (int T = 0; T < 4; ++T)
#pragma unroll
    for (int m = 0; m < 4; ++m)
#pragma unroll
      for (int rp = 0; rp < 2; ++rp) {
        const int w = 8 * T + 2 * m + rp;
        const unsigned xu = U4GET(xv[w >> 2], w & 3);
        const float xl = __uint_as_float(xu << 16);
        const float xh = __uint_as_float(xu & 0xffff0000u);
        v0a[T][m][rp] = dd[T][4 * m + 2 * rp] * xl;
        v1a[T][m][rp] = dd[T][4 * m + 2 * rp + 1] * xh;
      }
  // ---- per-chain renorm every 4th step ----
  if (donorm) {
    unsigned eb = __float_as_uint(v0a[0][0][0]);  // state 0 (h=0 lanes)
    unsigned ec = eb;
    asm("v_permlane32_swap_b32 %0, %1" : "+v"(eb), "+v"(ec));  // bcast lo half
    const int n = (int)((eb >> 23) & 0xFFu) - 127;
    cloc += n;
    const int nn = -n;
#pragma unroll
    for (int T = 0; T < 4; ++T)
#pragma unroll
      for (int m = 0; m < 4; ++m)
#pragma unroll
        for (int rp = 0; rp < 2; ++rp) {
          v0a[T][m][rp] = ldexpf(v0a[T][m][rp], nn);
          v1a[T][m][rp] = ldexpf(v1a[T][m][rp], nn);
        }
  }
  if (BWD) {
    // activation at t == len-1: U = x * exp(etrans)  (rare branch)
    const bool act = (t == lm1);
    if (__any(act)) {
#pragma unroll
      for (int T = 0; T < 4; ++T)
#pragma unroll
        for (int m = 0; m < 4; ++m)
#pragma unroll
          for (int rp = 0; rp < 2; ++rp) {
            const int j0 = 32 * T + 8 * m + 4 * h + 2 * rp;
            const int w = 8 * T + 2 * m + rp;
            const unsigned xu = U4GET(xv[w >> 2], w & 3);
            const float xl = __uint_as_float(xu << 16);
            const float xh = __uint_as_float(xu & 0xffff0000u);
            const float a0 = xl * __expf(etrans[j0]);
            const float a1 = xh * __expf(etrans[j0 + 1]);
            v0a[T][m][rp] = act ? a0 : v0a[T][m][rp];
            v1a[T][m][rp] = act ? a1 : v1a[T][m][rp];
          }
      cloc = act ? 0 : cloc;
    }
    if (dfinal) {  // t == 258: dump U_258 for chains len >= 259
      const bool dmp = (lm1 >= 258);
      if (__any(dmp)) {
        if (dmp) {
          dump_state(v0a, v1a, OUT, b, h);
          if (h == 0) CNT[b] = cloc;
        }
      }
    }
  } else {
    // freeze-dump alpha at t == len-1 (or final step for len >= 259 chains)
    const bool fz = (t == lm1) || (dfinal && lm1 > t);
    if (__any(fz)) {
      if (fz) {
        dump_state(v0a, v1a, OUT, b, h);
        if (h == 0) CNT[b] = cloc;
      }
    }
  }
  cvtperm(v0a, v1a, Bq);
}

// ---------- Phase 2: single-wave barrier-free fwd/bwd recursions -----------
// Blocks 0..7: forward (t=1..min(len-1,257));  blocks 8..15: backward
// (t=smax-1 .. 258).  One wave owns 32 chains; state lives in registers as
// the MFMA B-operand; D->B relayout via 16 x v_permlane32_swap_b32.
__global__ __launch_bounds__(64, 1) void crf_fb2(
    const float* __restrict__ emit, const float* __restrict__ trans,
    const float* __restrict__ strans, const float* __restrict__ etrans,
    const uint4* __restrict__ Xq, const int* __restrict__ lens,
    float* __restrict__ AF, int* __restrict__ CF, float* __restrict__ BU,
    int* __restrict__ CB) {
  const int l = threadIdx.x & 63;
  const int c5 = l & 31, h = l >> 5;
  const bool bwd = (blockIdx.x >= G2);
  const int g = bwd ? (int)blockIdx.x - G2 : (int)blockIdx.x;
  const int b = g * 32 + c5;

  const int len = lens[b];
  const int lm1 = len - 1;
  int sm = len;
#pragma unroll
  for (int mk = 1; mk < 32; mk <<= 1) {
    int o = __shfl_xor(sm, mk, 64);
    sm = o > sm ? o : sm;
  }

  // E fragments as MFMA A-operand: eA[T][kt] elem jj = E-orient value at
  // (M row 32T+c5, K 16kt+8h+jj).
  short8_t eA[4][8];
#pragma unroll
  for (int T = 0; T < 4; ++T)
#pragma unroll
    for (int kt = 0; kt < 8; ++kt) {
      short8_t f;
#pragma unroll
      for (int jj = 0; jj < 8; ++jj) {
        const int jm = 32 * T + c5;
        const int kk = 16 * kt + 8 * h + jj;
        const float tv = bwd ? trans[jm * NN + kk] : trans[kk * NN + jm];
        f[jj] = (short)f2bf(__expf(tv));
      }
      eA[T][kt] = f;
    }

  f32x16 kZ;
#pragma unroll
  for (int i = 0; i < 16; ++i) kZ[i] = 0.f;

  const uint4* Xg = Xq + (size_t)g * TT * 512 + l;
  uint4 Bq[8];
  int cloc = 0;

  if (!bwd) {
    // ---- init alpha_0 ----
    float v0a[4][4][2], v1a[4][4][2];
#pragma unroll
    for (int T = 0; T < 4; ++T)
#pragma unroll
      for (int m = 0; m < 4; ++m)
#pragma unroll
        for (int rp = 0; rp < 2; ++rp) {
          const int j0 = 32 * T + 8 * m + 4 * h + 2 * rp;
          v0a[T][m][rp] = __expf(strans[j0] + emit[(size_t)b * NN + j0]);
          v1a[T][m][rp] = __expf(strans[j0 + 1] + emit[(size_t)b * NN + j0 + 1]);
        }
    if (__any(lm1 == 0)) {
      if (lm1 == 0) {
        dump_state(v0a, v1a, AF, b, h);
        if (h == 0) CF[b] = 0;
      }
    }
    cvtperm(v0a, v1a, Bq);

    const int Lmax = sm < 258 ? sm : 258;
    const int S = Lmax - 1;  // steps t = 1..S
    uint4 xbuf0[8], xbuf1[8];
    {
      const uint4* p0 = Xg + (size_t)1 * 512;
      const uint4* p1 = Xg + (size_t)2 * 512;
#pragma unroll
      for (int i = 0; i < 8; ++i) xbuf0[i] = p0[i * 64];
#pragma unroll
      for (int i = 0; i < 8; ++i) xbuf1[i] = p1[i * 64];
    }
    int s = 0;
#define STEPF(SS, NRM, XB)                                               \
  fb_step<false>(1 + (SS), (NRM), ((SS) + 1 == S),                       \
                 ((SS) + 3 < TT ? (SS) + 3 : TT - 1), lm1, c5, h, b, Xg, \
                 eA, kZ, Bq, XB, cloc, etrans, AF, CF)
    for (; s + 4 <= S; s += 4) {
      STEPF(s + 0, false, xbuf0);
      STEPF(s + 1, false, xbuf1);
      STEPF(s + 2, false, xbuf0);
      STEPF(s + 3, true, xbuf1);
    }
    if (s + 0 < S) STEPF(s + 0, false, xbuf0);
    if (s + 1 < S) STEPF(s + 1, false, xbuf1);
    if (s + 2 < S) STEPF(s + 2, false, xbuf0);
#undef STEPF
  } else {
#pragma unroll
    for (int k = 0; k < 8; ++k)
      Bq[k] = make_uint4(0x3F803F80u, 0x3F803F80u, 0x3F803F80u, 0x3F803F80u);
    if (sm >= 259) {
      const int tstart = sm - 1;
      const int S = tstart - 257;  // steps t = tstart..258
      uint4 xbuf0[8], xbuf1[8];
      {
        const uint4* p0 = Xg + (size_t)tstart * 512;
        const int t1 = tstart - 1;
        const uint4* p1 = Xg + (size_t)t1 * 512;
#pragma unroll
        for (int i = 0; i < 8; ++i) xbuf0[i] = p0[i * 64];
#pragma unroll
        for (int i = 0; i < 8; ++i) xbuf1[i] = p1[i * 64];
      }
      int s = 0;
#define STEPB(SS, NRM, XB)                                                  \
  fb_step<true>(tstart - (SS), (NRM), ((SS) + 1 == S),                      \
                (tstart - (SS) - 2 > 0 ? tstart - (SS) - 2 : 0), lm1, c5,   \
                h, b, Xg, eA, kZ, Bq, XB, cloc, etrans, BU, CB)
      for (; s + 4 <= S; s += 4) {
        STEPB(s + 0, false, xbuf0);
        STEPB(s + 1, false, xbuf1);
        STEPB(s + 2, false, xbuf0);
        STEPB(s + 3, true, xbuf1);
      }
      if (s + 0 < S) STEPB(s + 0, false, xbuf0);
      if (s + 1 < S) STEPB(s + 1, false, xbuf1);
      if (s + 2 < S) STEPB(s + 2, false, xbuf0);
#undef STEPB
    }
  }
}

// ---------- Phase 3: combine (unchanged; AF/BU are in p-space) -------------
__global__ __launch_bounds__(256) void crf_comb(
    const float* __restrict__ trans, const float* __restrict__ etrans,
    const int* __restrict__ lens, const float* __restrict__ AF,
    const int* __restrict__ CF, const float* __restrict__ BU,
    const int* __restrict__ CB, float* __restrict__ ws,
    float* __restrict__ out) {
  __shared__ __align__(16) unsigned short sU[MW * STH];
  __shared__ float sRed[4][MW][2];
  __shared__ int slen[MW];
  const int tid = threadIdx.x;
  const int w = tid >> 6, l = tid & 63, c = l & 15, qd = l >> 4;
  const int g = blockIdx.x, bg = g * MW;

  if (tid < MW) slen[tid] = lens[bg + tid];
  {
    const int m = tid & 15, pbase = (tid >> 4) * 8;
#pragma unroll
    for (int pp = 0; pp < 8; ++pp) {
      int p = pbase + pp;
      sU[m * STH + p] = f2bf(BU[(size_t)(bg + m) * NN + p]);
    }
  }
  short8_t eB[4][2];
#pragma unroll
  for (int kt = 0; kt < 4; ++kt)
#pragma unroll
    for (int u = 0; u < 2; ++u)
#pragma unroll
      for (int jj = 0; jj < 8; ++jj) {
        int kp = kt * 32 + qd * 8 + jj;
        int a_ = orig_j(kp);
        int b_ = 32 * w + 16 * u + c;
        eB[kt][u][jj] = (short)f2bf(__expf(trans[b_ * NN + a_]));  // bwd orient
      }
  const float eet0 = __expf(etrans[32 * w + c]);
  const float eet1 = __expf(etrans[32 * w + 16 + c]);
  __syncthreads();

  const short8_t A0 = *(const short8_t*)&sU[c * STH + 0 + qd * 8];
  const short8_t A1 = *(const short8_t*)&sU[c * STH + 32 + qd * 8];
  const short8_t A2 = *(const short8_t*)&sU[c * STH + 64 + qd * 8];
  const short8_t A3 = *(const short8_t*)&sU[c * STH + 96 + qd * 8];
  f32x4 ac0 = {0.f, 0.f, 0.f, 0.f}, ac1 = {0.f, 0.f, 0.f, 0.f};
  ac0 = __builtin_amdgcn_mfma_f32_16x16x32_bf16(A0, eB[0][0], ac0, 0, 0, 0);
  ac1 = __builtin_amdgcn_mfma_f32_16x16x32_bf16(A0, eB[0][1], ac1, 0, 0, 0);
  ac0 = __builtin_amdgcn_mfma_f32_16x16x32_bf16(A1, eB[1][0], ac0, 0, 0, 0);
  ac1 = __builtin_amdgcn_mfma_f32_16x16x32_bf16(A1, eB[1][1], ac1, 0, 0, 0);
  ac0 = __builtin_amdgcn_mfma_f32_16x16x32_bf16(A2, eB[2][0], ac0, 0, 0, 0);
  ac1 = __builtin_amdgcn_mfma_f32_16x16x32_bf16(A2, eB[2][1], ac1, 0, 0, 0);
  ac0 = __builtin_amdgcn_mfma_f32_16x16x32_bf16(A3, eB[3][0], ac0, 0, 0, 0);
  ac1 = __builtin_amdgcn_mfma_f32_16x16x32_bf16(A3, eB[3][1], ac1, 0, 0, 0);

#pragma unroll
  for (int r_ = 0; r_ < 4; ++r_) {
    float a0 = AF[(size_t)(bg + 4 * qd + r_) * NN + 32 * w + 2 * c];
    float a1 = AF[(size_t)(bg + 4 * qd + r_) * NN + 32 * w + 2 * c + 1];
    float dB = a0 * ac0[r_] + a1 * ac1[r_];
    float dA = a0 * eet0 + a1 * eet1;
#pragma unroll
    for (int mk = 1; mk < 16; mk <<= 1) {
      dB += __shfl_xor(dB, mk, 64);
      dA += __shfl_xor(dA, mk, 64);
    }
    if (c == 0) {
      sRed[w][4 * qd + r_][0] = dB;
      sRed[w][4 * qd + r_][1] = dA;
    }
  }
  __syncthreads();
  if (tid < MW) {
    float DB = sRed[0][tid][0] + sRed[1][tid][0] + sRed[2][tid][0] + sRed[3][tid][0];
    float DA = sRed[0][tid][1] + sRed[1][tid][1] + sRed[2][tid][1] + sRed[3][tid][1];
    const int len = slen[tid];
    const float LN2 = 0.6931471805599453f;
    float logZ;
    if (len >= 259)
      logZ = LN2 * (float)(CF[bg + tid] + CB[bg + tid]) + __logf(DB);
    else
      logZ = LN2 * (float)CF[bg + tid] + __logf(DA);
    atomicAdd(&ws[0], logZ);
  }
  __syncthreads();
  if (tid == 0) {
    __threadfence();
    unsigned old = atomicAdd((unsigned*)ws + 3, 1u);
    if (old == NWG - 1) {
      float zz = atomicAdd(&ws[0], 0.f);
      float ss = atomicAdd(&ws[1], 0.f);
      out[0] = (zz - ss) * (1.0f / (float)BB);
    }
  }
}

// ---------- Fallback (Round-5 fused kernel, verified) ----------------------
__global__ __launch_bounds__(256, 1) void crf_fused_fb(
    const float* __restrict__ emit, const int* __restrict__ target,
    const void* __restrict__ maskp, const float* __restrict__ trans,
    const float* __restrict__ strans, const float* __restrict__ etrans,
    float* __restrict__ ws, float* __restrict__ out) {
  __shared__ __align__(16) unsigned short sV[2][MW * STH];
  __shared__ __align__(16) int nrm[2][MW];
  __shared__ __align__(16) int sC[MW];
  __shared__ int slen[MW];
  __shared__ float sscore;
  __shared__ int smax;

  const int tid = threadIdx.x;
  const int w = tid >> 6;
  const int l = tid & 63;
  const int c = l & 15;
  const int qd = l >> 4;
  const int bg = blockIdx.x * MW;

  if (tid < MW) slen[tid] = 0;
  if (tid == 0) { sscore = 0.f; smax = 0; }
  __syncthreads();

  const unsigned char* mk8 = (const unsigned char*)maskp;
  const int* mk32 = (const int*)maskp;
  const bool is_u8 = (mk8[1] != 0);
  {
    const int mi = tid & 15;
    const int b = bg + mi;
    const int t0 = (tid >> 4) * 32;
    int cnt = 0;
    float sc = 0.f;
    for (int s = 0; s < 32; ++s) {
      int t = t0 + s;
      int m = is_u8 ? (mk8[t * BB + b] != 0) : (mk32[t * BB + b] != 0);
      if (m) {
        cnt++;
        int tg = target[t * BB + b];
        float v = emit[((size_t)t * BB + b) * NN + tg];
        v += (t > 0) ? trans[target[(t - 1) * BB + b] * NN + tg] : strans[tg];
        int mn = (t + 1 < TT) ? (is_u8 ? (mk8[(t + 1) * BB + b] != 0)
                                       : (mk32[(t + 1) * BB + b] != 0))
                              : 0;
        if (!mn) v += etrans[tg];
        sc += v;
      }
    }
    atomicAdd(&slen[mi], cnt);
    atomicAdd(&sscore, sc);
  }

  short8_t eB[4][2];
#pragma unroll
  for (int kt = 0; kt < 4; ++kt)
#pragma unroll
    for (int u = 0; u < 2; ++u)
#pragma unroll
      for (int jj = 0; jj < 8; ++jj) {
        int kp = kt * 32 + qd * 8 + jj;
        int i = orig_j(kp);
        int j = 32 * w + 16 * u + c;
        eB[kt][u][jj] = (short)f2bf(__expf(trans[i * NN + j]));
      }

  {
    const int m = tid & 15;
    const int b = bg + m;
    const int pbase = (tid >> 4) * 8;
#pragma unroll
    for (int pp = 0; pp < 8; ++pp) {
      int p = pbase + pp;
      int j = orig_j(p);
      float v = __expf(strans[j] + emit[(size_t)b * NN + j]);
      sV[0][m * STH + p] = f2bf(v);
      if (p == 0)
        nrm[0][m] = ((int)((__float_as_uint(v) >> 23) & 0xFF)) - 120;
    }
  }
  __syncthreads();

  if (tid < MW) atomicMax(&smax, slen[tid]);
  if (tid == 0) atomicAdd(&ws[1], sscore);
  __syncthreads();
  const int Lmax = smax;
  int lenr[4];
#pragma unroll
  for (int r = 0; r < 4; ++r) lenr[r] = slen[4 * qd + r];

  int off8[8];
#pragma unroll
  for (int r = 0; r < 4; ++r)
#pragma unroll
    for (int u = 0; u < 2; ++u)
      off8[r * 2 + u] = (bg + 4 * qd + r) * NN + 32 * w + 16 * u + c;

  float ra[8], rb[8], xv[8];
  {
#pragma unroll
    for (int i = 0; i < 8; ++i) ra[i] = emit[(size_t)1 * BB * NN + off8[i]];
#pragma unroll
    for (int i = 0; i < 8; ++i) rb[i] = emit[(size_t)2 * BB * NN + off8[i]];
#pragma unroll
    for (int i = 0; i < 8; ++i) xv[i] = __expf(ra[i]);
  }
  int cloc[4] = {0, 0, 0, 0};
  const bool nwriter = (w == 0 && c == 0);

#define CRF_STEP(T_, PIN, POUT, RL, RO)                                       \
  do {                                                                        \
    int tl = ((T_) + 2 < TT) ? (T_) + 2 : TT - 1;                             \
    const size_t gbase = (size_t)tl * (BB * NN);                              \
    _Pragma("unroll") for (int i_ = 0; i_ < 8; ++i_)                          \
        RL[i_] = emit[gbase + off8[i_]];                                      \
    const short8_t A0 = *(const short8_t*)&sV[PIN][c * STH + 0 + qd * 8];     \
    const short8_t A1 = *(const short8_t*)&sV[PIN][c * STH + 32 + qd * 8];    \
    const short8_t A2 = *(const short8_t*)&sV[PIN][c * STH + 64 + qd * 8];    \
    const short8_t A3 = *(const short8_t*)&sV[PIN][c * STH + 96 + qd * 8];    \
    const int4 nr = *(const int4*)&nrm[PIN][4 * qd];                          \
    f32x4 ac0 = {0.f, 0.f, 0.f, 0.f}, ac1 = {0.f, 0.f, 0.f, 0.f};             \
    ac0 = __builtin_amdgcn_mfma_f32_16x16x32_bf16(A0, eB[0][0], ac0, 0, 0, 0);\
    ac1 = __builtin_amdgcn_mfma_f32_16x16x32_bf16(A0, eB[0][1], ac1, 0, 0, 0);\
    ac0 = __builtin_amdgcn_mfma_f32_16x16x32_bf16(A1, eB[1][0], ac0, 0, 0, 0);\
    ac1 = __builtin_amdgcn_mfma_f32_16x16x32_bf16(A1, eB[1][1], ac1, 0, 0, 0);\
    ac0 = __builtin_amdgcn_mfma_f32_16x16x32_bf16(A2, eB[2][0], ac0, 0, 0, 0);\
    ac1 = __builtin_amdgcn_mfma_f32_16x16x32_bf16(A2, eB[2][1], ac1, 0, 0, 0);\
    ac0 = __builtin_amdgcn_mfma_f32_16x16x32_bf16(A3, eB[3][0], ac0, 0, 0, 0);\
    ac1 = __builtin_amdgcn_mfma_f32_16x16x32_bf16(A3, eB[3][1], ac1, 0, 0, 0);\
    const int nA[4] = {nr.x, nr.y, nr.z, nr.w};                               \
    int nnw[4];                                                               \
    _Pragma("unroll") for (int r_ = 0; r_ < 4; ++r_) {                        \
      float y0 = ac0[r_] * xv[2 * r_];                                        \
      float y1 = ac1[r_] * xv[2 * r_ + 1];                                    \
      float v0 = ldexpf(y0, -nA[r_]);                                         \
      float v1 = ldexpf(y1, -nA[r_]);                                         \
      if ((T_) < lenr[r_]) {                                                  \
        unsigned pk = (unsigned)f2bf(v0) | ((unsigned)f2bf(v1) << 16);        \
        *(unsigned*)&sV[POUT][(4 * qd + r_) * STH + 32 * w + 2 * c] = pk;     \
        cloc[r_] += nA[r_];                                                   \
      }                                                                       \
      nnw[r_] = ((int)((__float_as_uint(v0) >> 23) & 0xFF)) - 120;            \
    }                                                                         \
    if (nwriter)                                                              \
      *(int4*)&nrm[POUT][4 * qd] = make_int4(nnw[0], nnw[1], nnw[2], nnw[3]); \
    _Pragma("unroll") for (int i_ = 0; i_ < 8; ++i_)                          \
        xv[i_] = __expf(RO[i_]);                                              \
    __syncthreads();                                                          \
  } while (0)

  for (int t = 1; t < Lmax; t += 2) {
    CRF_STEP(t, 0, 1, ra, rb);
    if (t + 1 < Lmax) {
      CRF_STEP(t + 1, 1, 0, rb, ra);
    }
  }
#undef CRF_STEP

  if (nwriter) *(int4*)&sC[4 * qd] = make_int4(cloc[0], cloc[1], cloc[2], cloc[3]);
  __syncthreads();
  {
    const int m = tid >> 4, i16 = tid & 15;
    const int pb = (slen[m] - 1) & 1;
    float s = 0.f;
#pragma unroll
    for (int pp = 0; pp < 8; ++pp) {
      int p = i16 * 8 + pp;
      int j = orig_j(p);
      s += bf2f(sV[pb][m * STH + p]) * __expf(etrans[j]);
    }
    s += __shfl_xor(s, 1, 64);
    s += __shfl_xor(s, 2, 64);
    s += __shfl_xor(s, 4, 64);
    s += __shfl_xor(s, 8, 64);
    if (i16 == 0)
      atomicAdd(&ws[0], (float)sC[m] * 0.69314718f + __logf(s));
  }
  __syncthreads();
  if (tid == 0) {
    __threadfence();
    unsigned old = atomicAdd((unsigned*)ws + 3, 1u);
    if (old == NWG - 1) {
      float zz = atomicAdd(&ws[0], 0.f);
      float ss = atomicAdd(&ws[1], 0.f);
      out[0] = (zz - ss) * (1.0f / (float)BB);
    }
  }
}

extern "C" void kernel_launch(void* const* d_in, const int* in_sizes, int n_in,
                              void* d_out, int out_size, void* d_ws, size_t ws_size,
                              hipStream_t stream) {
  const float* emit = (const float*)d_in[0];
  const int* target = (const int*)d_in[1];
  const void* mask = (const void*)d_in[2];
  const float* trans = (const float*)d_in[3];
  const float* strans = (const float*)d_in[4];
  const float* etrans = (const float*)d_in[5];
  float* ws = (float*)d_ws;
  float* out = (float*)d_out;

  const size_t need = (size_t)XQ_OFF + XQ_SZ;
  hipMemsetAsync(d_ws, 0, 16, stream);
  if (ws_size >= need) {
    int* lens = (int*)((char*)d_ws + LENS_OFF);
    float* AF = (float*)((char*)d_ws + AF_OFF);
    int* CF = (int*)((char*)d_ws + CF_OFF);
    float* BU = (float*)((char*)d_ws + BU_OFF);
    int* CB = (int*)((char*)d_ws + CB_OFF);
    uint4* Xq = (uint4*)((char*)d_ws + XQ_OFF);
    crf_expemit2<<<G2 * TT / 4, 256, 0, stream>>>(emit, Xq);
    crf_score_k<<<TT, BB, 0, stream>>>(emit, target, mask, trans, strans,
                                       etrans, ws, lens);
    crf_fb2<<<2 * G2, 64, 0, stream>>>(emit, trans, strans, etrans,
                                       (const uint4*)Xq, lens, AF, CF, BU, CB);
    crf_comb<<<NWG, 256, 0, stream>>>(trans, etrans, lens, AF, CF, BU, CB, ws,
                                      out);
  } else {
    crf_fused_fb<<<NWG, 256, 0, stream>>>(emit, target, mask, trans, strans,
                                          etrans, ws, out);
  }
}

// Round 2
// 318.034 us; speedup vs baseline: 1.3158x; 1.3158x over previous
//
#include <hip/hip_runtime.h>

#define TT 512
#define BB 256
#define NN 128
#define MW 16            // chains per group
#define NWG (BB / MW)    // 16 chain-groups
#define STH 144          // state row stride in halves (288 B, 16B-aligned)

// ws layout (bytes)
#define LENS_OFF 256
#define AF_OFF 2048
#define CF_OFF (AF_OFF + BB * NN * 4)
#define BU_OFF (CF_OFF + 1024)
#define CB_OFF (BU_OFF + BB * NN * 4)
#define XQ_OFF (CB_OFF + 1024)
#define XQ_SZ ((size_t)TT * BB * NN * 2)

typedef __attribute__((ext_vector_type(8))) short short8_t;
typedef __attribute__((ext_vector_type(4))) float f32x4;

__device__ __forceinline__ unsigned short f2bf(float f) {
  unsigned u = __float_as_uint(f);
  return (unsigned short)((u + 0x7FFF + ((u >> 16) & 1)) >> 16);  // RNE
}
__device__ __forceinline__ float bf2f(unsigned short h) {
  return __uint_as_float(((unsigned)h) << 16);
}
// storage position p <-> original index:  idx = 32w+16u+c  <->  p = 32w+2c+u
__device__ __forceinline__ int orig_j(int p) {
  return 32 * (p >> 5) + 16 * (p & 1) + ((p >> 1) & 15);
}

// ---------- Phase 1a: X[g][t][tid] = exp(emit) as bf16, consumer layout ----
__global__ __launch_bounds__(256) void crf_expemit(
    const float* __restrict__ emit, uint4* __restrict__ Xq) {
  const int bid = blockIdx.x;
  const int g = bid >> 9;
  const int t = bid & (TT - 1);
  const int tid = threadIdx.x;
  const int w = tid >> 6, l = tid & 63, qd = l >> 4, c = l & 15;
  const int bg = g * MW;
  unsigned pk[4];
#pragma unroll
  for (int r = 0; r < 4; ++r) {
    const size_t row = ((size_t)t * BB + bg + 4 * qd + r) * NN + 32 * w + c;
    float v0 = __expf(emit[row]);
    float v1 = __expf(emit[row + 16]);
    pk[r] = (unsigned)f2bf(v0) | ((unsigned)f2bf(v1) << 16);
  }
  Xq[((size_t)g * TT + t) * 256 + tid] = make_uint4(pk[0], pk[1], pk[2], pk[3]);
}

// ---------- Phase 1b: gold score + per-chain lengths (parallel) ------------
__global__ __launch_bounds__(BB) void crf_score_k(
    const float* __restrict__ emit, const int* __restrict__ target,
    const void* __restrict__ maskp, const float* __restrict__ trans,
    const float* __restrict__ strans, const float* __restrict__ etrans,
    float* __restrict__ ws, int* __restrict__ lens) {
  __shared__ float rf[4];
  const int b = threadIdx.x;
  const int t = blockIdx.x;
  const unsigned char* mk8 = (const unsigned char*)maskp;
  const int* mk32 = (const int*)maskp;
  const bool is_u8 = (mk8[1] != 0);

  int m = is_u8 ? (mk8[t * BB + b] != 0) : (mk32[t * BB + b] != 0);
  float v = 0.f;
  if (m) {
    int tg = target[t * BB + b];
    v = emit[((size_t)t * BB + b) * NN + tg];
    v += (t > 0) ? trans[target[(t - 1) * BB + b] * NN + tg] : strans[tg];
    int mn = (t + 1 < TT) ? (is_u8 ? (mk8[(t + 1) * BB + b] != 0)
                                   : (mk32[(t + 1) * BB + b] != 0))
                          : 0;
    if (!mn) {  // prefix-mask edge = last valid step
      v += etrans[tg];
      lens[b] = t + 1;
    }
  }
#pragma unroll
  for (int off = 32; off; off >>= 1) v += __shfl_down(v, off, 64);
  if ((b & 63) == 0) rf[b >> 6] = v;
  __syncthreads();
  if (b == 0) atomicAdd(&ws[1], rf[0] + rf[1] + rf[2] + rf[3]);
}

// ---------- Phase 2: fused fwd+bwd recursions, 512 threads/block -----------
// Waves 0-3 (tid<256): forward alpha-recursion t=1..min(len-1,257).
// Waves 4-7 (tid>=256): backward U-recursion t=smax-1 down to 258.
// Separate LDS state per half; one shared barrier per step keeps one fwd +
// one bwd wave co-resident per SIMD for latency hiding.  Step body identical
// to the verified R0 kernel.
__global__ __launch_bounds__(512, 1) void crf_fbf(
    const float* __restrict__ emit, const float* __restrict__ trans,
    const float* __restrict__ strans, const float* __restrict__ etrans,
    const uint4* __restrict__ Xq, const int* __restrict__ lens,
    float* __restrict__ AF, int* __restrict__ CF,
    float* __restrict__ BU, int* __restrict__ CB) {
  __shared__ __align__(16) unsigned short sV[2][2][MW * STH];  // [half][parity]
  __shared__ __align__(16) int nrm[2][2][MW];
  __shared__ __align__(16) int sC[2][MW];
  __shared__ int slen[MW];
  __shared__ int smax_s;

  const int tid = threadIdx.x;
  const int half = tid >> 8;      // 0 = fwd, 1 = bwd
  const int tid2 = tid & 255;
  const int w = tid2 >> 6;
  const int l = tid2 & 63;
  const int c = l & 15;
  const int qd = l >> 4;
  const bool bwd = (half == 1);
  const int g = blockIdx.x;
  const int bg = g * MW;

  unsigned short(*sVh)[MW * STH] = sV[half];
  int(*nrmh)[MW] = nrm[half];

  if (tid == 0) smax_s = 0;
  if (tid < MW) slen[tid] = lens[bg + tid];
  __syncthreads();
  if (tid < MW) atomicMax(&smax_s, slen[tid]);

  // ---- E fragments (bwd: transposed orientation) ----
  short8_t eB[4][2];
#pragma unroll
  for (int kt = 0; kt < 4; ++kt)
#pragma unroll
    for (int u = 0; u < 2; ++u)
#pragma unroll
      for (int jj = 0; jj < 8; ++jj) {
        int kp = kt * 32 + qd * 8 + jj;
        int a_ = orig_j(kp);
        int b_ = 32 * w + 16 * u + c;
        float tv = bwd ? trans[b_ * NN + a_] : trans[a_ * NN + b_];
        eB[kt][u][jj] = (short)f2bf(__expf(tv));
      }
  const float eet0 = __expf(etrans[32 * w + c]);
  const float eet1 = __expf(etrans[32 * w + 16 + c]);

  // ---- init state ----
  {
    const int m = tid2 & 15;
    const int pbase = (tid2 >> 4) * 8;
    if (!bwd) {
      const int b = bg + m;
#pragma unroll
      for (int pp = 0; pp < 8; ++pp) {
        int p = pbase + pp;
        int j = orig_j(p);
        float v = __expf(strans[j] + emit[(size_t)b * NN + j]);
        sVh[0][m * STH + p] = f2bf(v);
        if (p == 0)
          nrmh[0][m] = ((int)((__float_as_uint(v) >> 23) & 0xFF)) - 120;
      }
    } else {
#pragma unroll
      for (int pp = 0; pp < 8; ++pp) {
        int p = pbase + pp;
        sVh[0][m * STH + p] = 0x3F80;  // 1.0 bf16
        sVh[1][m * STH + p] = 0x3F80;
        if (p == 0) { nrmh[0][m] = 0; nrmh[1][m] = 0; }
      }
    }
  }
  __syncthreads();
  const int smax = smax_s;
  int lm1[4];
#pragma unroll
  for (int r = 0; r < 4; ++r) lm1[r] = slen[4 * qd + r] - 1;

  int cloc[4] = {0, 0, 0, 0};
  const bool nwriter = (w == 0 && c == 0);
  const uint4* Xg = Xq + (size_t)g * TT * 256 + tid2;

  const int LmaxF = (smax < 258) ? smax : 258;
  const int NITf = LmaxF - 1;                       // fwd steps t = 1..LmaxF-1
  const int NITb = (smax >= 259) ? smax - 258 : 0;  // bwd steps t = smax-1..258
  const int NIT = NITf > NITb ? NITf : NITb;
  const int tstart = smax - 1;

  for (int tb = 0; tb < NIT; tb += 8) {
    uint4 xq[8];
#pragma unroll
    for (int k = 0; k < 8; ++k) {
      int t;
      if (!bwd) {
        t = 1 + tb + k;
        if (t > TT - 1) t = TT - 1;
      } else {
        t = tstart - (tb + k);
        if (t < 0) t = 0;
      }
      xq[k] = Xg[(size_t)t * 256];
    }
#pragma unroll
    for (int k = 0; k < 8; ++k) {
      const int it = tb + k;
      if (it >= NIT) break;  // NIT uniform across block: barrier-safe
      const bool active = bwd ? (it < NITb) : (it < NITf);
      if (active) {
        const int T_ = bwd ? (tstart - it) : (1 + it);
        const int POUT = T_ & 1, PIN = POUT ^ 1;
        const short8_t A0 = *(const short8_t*)&sVh[PIN][c * STH + 0 + qd * 8];
        const short8_t A1 = *(const short8_t*)&sVh[PIN][c * STH + 32 + qd * 8];
        const short8_t A2 = *(const short8_t*)&sVh[PIN][c * STH + 64 + qd * 8];
        const short8_t A3 = *(const short8_t*)&sVh[PIN][c * STH + 96 + qd * 8];
        const int4 nr = *(const int4*)&nrmh[PIN][4 * qd];
        f32x4 p0 = {0.f, 0.f, 0.f, 0.f}, q0 = {0.f, 0.f, 0.f, 0.f};
        f32x4 p1 = {0.f, 0.f, 0.f, 0.f}, q1 = {0.f, 0.f, 0.f, 0.f};
        p0 = __builtin_amdgcn_mfma_f32_16x16x32_bf16(A0, eB[0][0], p0, 0, 0, 0);
        p1 = __builtin_amdgcn_mfma_f32_16x16x32_bf16(A0, eB[0][1], p1, 0, 0, 0);
        q0 = __builtin_amdgcn_mfma_f32_16x16x32_bf16(A2, eB[2][0], q0, 0, 0, 0);
        q1 = __builtin_amdgcn_mfma_f32_16x16x32_bf16(A2, eB[2][1], q1, 0, 0, 0);
        p0 = __builtin_amdgcn_mfma_f32_16x16x32_bf16(A1, eB[1][0], p0, 0, 0, 0);
        p1 = __builtin_amdgcn_mfma_f32_16x16x32_bf16(A1, eB[1][1], p1, 0, 0, 0);
        q0 = __builtin_amdgcn_mfma_f32_16x16x32_bf16(A3, eB[3][0], q0, 0, 0, 0);
        q1 = __builtin_amdgcn_mfma_f32_16x16x32_bf16(A3, eB[3][1], q1, 0, 0, 0);
        const f32x4 ac0 = p0 + q0;
        const f32x4 ac1 = p1 + q1;
        const int nA[4] = {nr.x, nr.y, nr.z, nr.w};
        const unsigned xd[4] = {xq[k].x, xq[k].y, xq[k].z, xq[k].w};
        int nnw[4];
#pragma unroll
        for (int r_ = 0; r_ < 4; ++r_) {
          float x0 = __uint_as_float(xd[r_] << 16);
          float x1 = __uint_as_float(xd[r_] & 0xffff0000u);
          float v0, v1;
          const bool wr = (T_ <= lm1[r_]);
          if (!bwd) {
            v0 = ldexpf(ac0[r_] * x0, -nA[r_]);
            v1 = ldexpf(ac1[r_] * x1, -nA[r_]);
            if (wr) {
              unsigned pk = (unsigned)f2bf(v0) | ((unsigned)f2bf(v1) << 16);
              *(unsigned*)&sVh[POUT][(4 * qd + r_) * STH + 32 * w + 2 * c] = pk;
              cloc[r_] += nA[r_];
            }
          } else {
            const bool isact = (T_ == lm1[r_]);
            v0 = isact ? x0 * eet0 : ldexpf(ac0[r_] * x0, -nA[r_]);
            v1 = isact ? x1 * eet1 : ldexpf(ac1[r_] * x1, -nA[r_]);
            if (wr) {
              unsigned pk = (unsigned)f2bf(v0) | ((unsigned)f2bf(v1) << 16);
              *(unsigned*)&sVh[POUT][(4 * qd + r_) * STH + 32 * w + 2 * c] = pk;
              cloc[r_] = isact ? 0 : cloc[r_] + nA[r_];
            }
          }
          nnw[r_] = ((int)((__float_as_uint(v0) >> 23) & 0xFF)) - 120;
        }
        if (nwriter)
          *(int4*)&nrmh[POUT][4 * qd] =
              make_int4(nnw[0], nnw[1], nnw[2], nnw[3]);
      }
      __syncthreads();
    }
  }

  // ---- epilogue: dump per-chain state + pow2 counters to global ----
  if (nwriter)
    *(int4*)&sC[half][4 * qd] = make_int4(cloc[0], cloc[1], cloc[2], cloc[3]);
  __syncthreads();
  {
    const int m = tid2 >> 4, i16 = tid2 & 15;
    if (!bwd) {
      int nf = slen[m] - 1;
      if (nf > 257) nf = 257;
      const int pf = nf & 1;
#pragma unroll
      for (int pp = 0; pp < 8; ++pp) {
        int p = i16 * 8 + pp;
        AF[(size_t)(bg + m) * NN + p] = bf2f(sVh[pf][m * STH + p]);
      }
      if (i16 == 0) CF[bg + m] = sC[0][m];
    } else {
      // active chains all end at t=258 -> parity 0; inactive: init (unused)
#pragma unroll
      for (int pp = 0; pp < 8; ++pp) {
        int p = i16 * 8 + pp;
        BU[(size_t)(bg + m) * NN + p] = bf2f(sVh[0][m * STH + p]);
      }
      if (i16 == 0) CB[bg + m] = sC[1][m];
    }
  }
}

// ---------- Phase 3: combine.  logZ_b = ln2*(CF+CB) + ln(alpha_257 . E U_258)
// (len>=259) or ln2*CF + ln(alpha . exp(etrans)) (len<=258). ----------------
__global__ __launch_bounds__(256) void crf_comb(
    const float* __restrict__ trans, const float* __restrict__ etrans,
    const int* __restrict__ lens, const float* __restrict__ AF,
    const int* __restrict__ CF, const float* __restrict__ BU,
    const int* __restrict__ CB, float* __restrict__ ws,
    float* __restrict__ out) {
  __shared__ __align__(16) unsigned short sU[MW * STH];
  __shared__ float sRed[4][MW][2];
  __shared__ int slen[MW];
  const int tid = threadIdx.x;
  const int w = tid >> 6, l = tid & 63, c = l & 15, qd = l >> 4;
  const int g = blockIdx.x, bg = g * MW;

  if (tid < MW) slen[tid] = lens[bg + tid];
  {
    const int m = tid & 15, pbase = (tid >> 4) * 8;
#pragma unroll
    for (int pp = 0; pp < 8; ++pp) {
      int p = pbase + pp;
      sU[m * STH + p] = f2bf(BU[(size_t)(bg + m) * NN + p]);
    }
  }
  short8_t eB[4][2];
#pragma unroll
  for (int kt = 0; kt < 4; ++kt)
#pragma unroll
    for (int u = 0; u < 2; ++u)
#pragma unroll
      for (int jj = 0; jj < 8; ++jj) {
        int kp = kt * 32 + qd * 8 + jj;
        int a_ = orig_j(kp);
        int b_ = 32 * w + 16 * u + c;
        eB[kt][u][jj] = (short)f2bf(__expf(trans[b_ * NN + a_]));  // bwd orient
      }
  const float eet0 = __expf(etrans[32 * w + c]);
  const float eet1 = __expf(etrans[32 * w + 16 + c]);
  __syncthreads();

  const short8_t A0 = *(const short8_t*)&sU[c * STH + 0 + qd * 8];
  const short8_t A1 = *(const short8_t*)&sU[c * STH + 32 + qd * 8];
  const short8_t A2 = *(const short8_t*)&sU[c * STH + 64 + qd * 8];
  const short8_t A3 = *(const short8_t*)&sU[c * STH + 96 + qd * 8];
  f32x4 ac0 = {0.f, 0.f, 0.f, 0.f}, ac1 = {0.f, 0.f, 0.f, 0.f};
  ac0 = __builtin_amdgcn_mfma_f32_16x16x32_bf16(A0, eB[0][0], ac0, 0, 0, 0);
  ac1 = __builtin_amdgcn_mfma_f32_16x16x32_bf16(A0, eB[0][1], ac1, 0, 0, 0);
  ac0 = __builtin_amdgcn_mfma_f32_16x16x32_bf16(A1, eB[1][0], ac0, 0, 0, 0);
  ac1 = __builtin_amdgcn_mfma_f32_16x16x32_bf16(A1, eB[1][1], ac1, 0, 0, 0);
  ac0 = __builtin_amdgcn_mfma_f32_16x16x32_bf16(A2, eB[2][0], ac0, 0, 0, 0);
  ac1 = __builtin_amdgcn_mfma_f32_16x16x32_bf16(A2, eB[2][1], ac1, 0, 0, 0);
  ac0 = __builtin_amdgcn_mfma_f32_16x16x32_bf16(A3, eB[3][0], ac0, 0, 0, 0);
  ac1 = __builtin_amdgcn_mfma_f32_16x16x32_bf16(A3, eB[3][1], ac1, 0, 0, 0);

#pragma unroll
  for (int r_ = 0; r_ < 4; ++r_) {
    // alpha at cols i0 = 32w+c (p=32w+2c), i1 = 32w+16+c (p=32w+2c+1)
    float a0 = AF[(size_t)(bg + 4 * qd + r_) * NN + 32 * w + 2 * c];
    float a1 = AF[(size_t)(bg + 4 * qd + r_) * NN + 32 * w + 2 * c + 1];
    float dB = a0 * ac0[r_] + a1 * ac1[r_];
    float dA = a0 * eet0 + a1 * eet1;
#pragma unroll
    for (int mk = 1; mk < 16; mk <<= 1) {
      dB += __shfl_xor(dB, mk, 64);
      dA += __shfl_xor(dA, mk, 64);
    }
    if (c == 0) {
      sRed[w][4 * qd + r_][0] = dB;
      sRed[w][4 * qd + r_][1] = dA;
    }
  }
  __syncthreads();
  if (tid < MW) {
    float DB = sRed[0][tid][0] + sRed[1][tid][0] + sRed[2][tid][0] + sRed[3][tid][0];
    float DA = sRed[0][tid][1] + sRed[1][tid][1] + sRed[2][tid][1] + sRed[3][tid][1];
    const int len = slen[tid];
    const float LN2 = 0.6931471805599453f;
    float logZ;
    if (len >= 259)
      logZ = LN2 * (float)(CF[bg + tid] + CB[bg + tid]) + __logf(DB);
    else
      logZ = LN2 * (float)CF[bg + tid] + __logf(DA);
    atomicAdd(&ws[0], logZ);
  }
  __syncthreads();
  if (tid == 0) {
    __threadfence();
    unsigned old = atomicAdd((unsigned*)ws + 3, 1u);
    if (old == NWG - 1) {
      float zz = atomicAdd(&ws[0], 0.f);
      float ss = atomicAdd(&ws[1], 0.f);
      out[0] = (zz - ss) * (1.0f / (float)BB);
    }
  }
}

// ---------- Fallback (Round-5 fused kernel, verified) ----------------------
__global__ __launch_bounds__(256, 1) void crf_fused_fb(
    const float* __restrict__ emit, const int* __restrict__ target,
    const void* __restrict__ maskp, const float* __restrict__ trans,
    const float* __restrict__ strans, const float* __restrict__ etrans,
    float* __restrict__ ws, float* __restrict__ out) {
  __shared__ __align__(16) unsigned short sV[2][MW * STH];
  __shared__ __align__(16) int nrm[2][MW];
  __shared__ __align__(16) int sC[MW];
  __shared__ int slen[MW];
  __shared__ float sscore;
  __shared__ int smax;

  const int tid = threadIdx.x;
  const int w = tid >> 6;
  const int l = tid & 63;
  const int c = l & 15;
  const int qd = l >> 4;
  const int bg = blockIdx.x * MW;

  if (tid < MW) slen[tid] = 0;
  if (tid == 0) { sscore = 0.f; smax = 0; }
  __syncthreads();

  const unsigned char* mk8 = (const unsigned char*)maskp;
  const int* mk32 = (const int*)maskp;
  const bool is_u8 = (mk8[1] != 0);
  {
    const int mi = tid & 15;
    const int b = bg + mi;
    const int t0 = (tid >> 4) * 32;
    int cnt = 0;
    float sc = 0.f;
    for (int s = 0; s < 32; ++s) {
      int t = t0 + s;
      int m = is_u8 ? (mk8[t * BB + b] != 0) : (mk32[t * BB + b] != 0);
      if (m) {
        cnt++;
        int tg = target[t * BB + b];
        float v = emit[((size_t)t * BB + b) * NN + tg];
        v += (t > 0) ? trans[target[(t - 1) * BB + b] * NN + tg] : strans[tg];
        int mn = (t + 1 < TT) ? (is_u8 ? (mk8[(t + 1) * BB + b] != 0)
                                       : (mk32[(t + 1) * BB + b] != 0))
                              : 0;
        if (!mn) v += etrans[tg];
        sc += v;
      }
    }
    atomicAdd(&slen[mi], cnt);
    atomicAdd(&sscore, sc);
  }

  short8_t eB[4][2];
#pragma unroll
  for (int kt = 0; kt < 4; ++kt)
#pragma unroll
    for (int u = 0; u < 2; ++u)
#pragma unroll
      for (int jj = 0; jj < 8; ++jj) {
        int kp = kt * 32 + qd * 8 + jj;
        int i = orig_j(kp);
        int j = 32 * w + 16 * u + c;
        eB[kt][u][jj] = (short)f2bf(__expf(trans[i * NN + j]));
      }

  {
    const int m = tid & 15;
    const int b = bg + m;
    const int pbase = (tid >> 4) * 8;
#pragma unroll
    for (int pp = 0; pp < 8; ++pp) {
      int p = pbase + pp;
      int j = orig_j(p);
      float v = __expf(strans[j] + emit[(size_t)b * NN + j]);
      sV[0][m * STH + p] = f2bf(v);
      if (p == 0)
        nrm[0][m] = ((int)((__float_as_uint(v) >> 23) & 0xFF)) - 120;
    }
  }
  __syncthreads();

  if (tid < MW) atomicMax(&smax, slen[tid]);
  if (tid == 0) atomicAdd(&ws[1], sscore);
  __syncthreads();
  const int Lmax = smax;
  int lenr[4];
#pragma unroll
  for (int r = 0; r < 4; ++r) lenr[r] = slen[4 * qd + r];

  int off8[8];
#pragma unroll
  for (int r = 0; r < 4; ++r)
#pragma unroll
    for (int u = 0; u < 2; ++u)
      off8[r * 2 + u] = (bg + 4 * qd + r) * NN + 32 * w + 16 * u + c;

  float ra[8], rb[8], xv[8];
  {
#pragma unroll
    for (int i = 0; i < 8; ++i) ra[i] = emit[(size_t)1 * BB * NN + off8[i]];
#pragma unroll
    for (int i = 0; i < 8; ++i) rb[i] = emit[(size_t)2 * BB * NN + off8[i]];
#pragma unroll
    for (int i = 0; i < 8; ++i) xv[i] = __expf(ra[i]);
  }
  int cloc[4] = {0, 0, 0, 0};
  const bool nwriter = (w == 0 && c == 0);

#define CRF_STEP(T_, PIN, POUT, RL, RO)                                       \
  do {                                                                        \
    int tl = ((T_) + 2 < TT) ? (T_) + 2 : TT - 1;                             \
    const size_t gbase = (size_t)tl * (BB * NN);                              \
    _Pragma("unroll") for (int i_ = 0; i_ < 8; ++i_)                          \
        RL[i_] = emit[gbase + off8[i_]];                                      \
    const short8_t A0 = *(const short8_t*)&sV[PIN][c * STH + 0 + qd * 8];     \
    const short8_t A1 = *(const short8_t*)&sV[PIN][c * STH + 32 + qd * 8];    \
    const short8_t A2 = *(const short8_t*)&sV[PIN][c * STH + 64 + qd * 8];    \
    const short8_t A3 = *(const short8_t*)&sV[PIN][c * STH + 96 + qd * 8];    \
    const int4 nr = *(const int4*)&nrm[PIN][4 * qd];                          \
    f32x4 ac0 = {0.f, 0.f, 0.f, 0.f}, ac1 = {0.f, 0.f, 0.f, 0.f};             \
    ac0 = __builtin_amdgcn_mfma_f32_16x16x32_bf16(A0, eB[0][0], ac0, 0, 0, 0);\
    ac1 = __builtin_amdgcn_mfma_f32_16x16x32_bf16(A0, eB[0][1], ac1, 0, 0, 0);\
    ac0 = __builtin_amdgcn_mfma_f32_16x16x32_bf16(A1, eB[1][0], ac0, 0, 0, 0);\
    ac1 = __builtin_amdgcn_mfma_f32_16x16x32_bf16(A1, eB[1][1], ac1, 0, 0, 0);\
    ac0 = __builtin_amdgcn_mfma_f32_16x16x32_bf16(A2, eB[2][0], ac0, 0, 0, 0);\
    ac1 = __builtin_amdgcn_mfma_f32_16x16x32_bf16(A2, eB[2][1], ac1, 0, 0, 0);\
    ac0 = __builtin_amdgcn_mfma_f32_16x16x32_bf16(A3, eB[3][0], ac0, 0, 0, 0);\
    ac1 = __builtin_amdgcn_mfma_f32_16x16x32_bf16(A3, eB[3][1], ac1, 0, 0, 0);\
    const int nA[4] = {nr.x, nr.y, nr.z, nr.w};                               \
    int nnw[4];                                                               \
    _Pragma("unroll") for (int r_ = 0; r_ < 4; ++r_) {                        \
      float y0 = ac0[r_] * xv[2 * r_];                                        \
      float y1 = ac1[r_] * xv[2 * r_ + 1];                                    \
      float v0 = ldexpf(y0, -nA[r_]);                                         \
      float v1 = ldexpf(y1, -nA[r_]);                                         \
      if ((T_) < lenr[r_]) {                                                  \
        unsigned pk = (unsigned)f2bf(v0) | ((unsigned)f2bf(v1) << 16);        \
        *(unsigned*)&sV[POUT][(4 * qd + r_) * STH + 32 * w + 2 * c] = pk;     \
        cloc[r_] += nA[r_];                                                   \
      }                                                                       \
      nnw[r_] = ((int)((__float_as_uint(v0) >> 23) & 0xFF)) - 120;            \
    }                                                                         \
    if (nwriter)                                                              \
      *(int4*)&nrm[POUT][4 * qd] = make_int4(nnw[0], nnw[1], nnw[2], nnw[3]); \
    _Pragma("unroll") for (int i_ = 0; i_ < 8; ++i_)                          \
        xv[i_] = __expf(RO[i_]);                                              \
    __syncthreads();                                                          \
  } while (0)

  for (int t = 1; t < Lmax; t += 2) {
    CRF_STEP(t, 0, 1, ra, rb);
    if (t + 1 < Lmax) {
      CRF_STEP(t + 1, 1, 0, rb, ra);
    }
  }
#undef CRF_STEP

  if (nwriter) *(int4*)&sC[4 * qd] = make_int4(cloc[0], cloc[1], cloc[2], cloc[3]);
  __syncthreads();
  {
    const int m = tid >> 4, i16 = tid & 15;
    const int pb = (slen[m] - 1) & 1;
    float s = 0.f;
#pragma unroll
    for (int pp = 0; pp < 8; ++pp) {
      int p = i16 * 8 + pp;
      int j = orig_j(p);
      s += bf2f(sV[pb][m * STH + p]) * __expf(etrans[j]);
    }
    s += __shfl_xor(s, 1, 64);
    s += __shfl_xor(s, 2, 64);
    s += __shfl_xor(s, 4, 64);
    s += __shfl_xor(s, 8, 64);
    if (i16 == 0)
      atomicAdd(&ws[0], (float)sC[m] * 0.69314718f + __logf(s));
  }
  __syncthreads();
  if (tid == 0) {
    __threadfence();
    unsigned old = atomicAdd((unsigned*)ws + 3, 1u);
    if (old == NWG - 1) {
      float zz = atomicAdd(&ws[0], 0.f);
      float ss = atomicAdd(&ws[1], 0.f);
      out[0] = (zz - ss) * (1.0f / (float)BB);
    }
  }
}

extern "C" void kernel_launch(void* const* d_in, const int* in_sizes, int n_in,
                              void* d_out, int out_size, void* d_ws, size_t ws_size,
                              hipStream_t stream) {
  const float* emit = (const float*)d_in[0];
  const int* target = (const int*)d_in[1];
  const void* mask = (const void*)d_in[2];
  const float* trans = (const float*)d_in[3];
  const float* strans = (const float*)d_in[4];
  const float* etrans = (const float*)d_in[5];
  float* ws = (float*)d_ws;
  float* out = (float*)d_out;

  const size_t need = (size_t)XQ_OFF + XQ_SZ;
  hipMemsetAsync(d_ws, 0, 16, stream);
  if (ws_size >= need) {
    int* lens = (int*)((char*)d_ws + LENS_OFF);
    float* AF = (float*)((char*)d_ws + AF_OFF);
    int* CF = (int*)((char*)d_ws + CF_OFF);
    float* BU = (float*)((char*)d_ws + BU_OFF);
    int* CB = (int*)((char*)d_ws + CB_OFF);
    uint4* Xq = (uint4*)((char*)d_ws + XQ_OFF);
    crf_expemit<<<NWG * TT, 256, 0, stream>>>(emit, Xq);
    crf_score_k<<<TT, BB, 0, stream>>>(emit, target, mask, trans, strans,
                                       etrans, ws, lens);
    crf_fbf<<<NWG, 512, 0, stream>>>(emit, trans, strans, etrans,
                                     (const uint4*)Xq, lens, AF, CF, BU, CB);
    crf_comb<<<NWG, 256, 0, stream>>>(trans, etrans, lens, AF, CF, BU, CB, ws,
                                      out);
  } else {
    crf_fused_fb<<<NWG, 256, 0, stream>>>(emit, target, mask, trans, strans,
                                          etrans, ws, out);
  }
}

// Round 3
// 239.342 us; speedup vs baseline: 1.7484x; 1.3288x over previous
//
#include <hip/hip_runtime.h>

#define TT 512
#define BB 256
#define NN 128
#define MW 16            // chains per group
#define NWG (BB / MW)    // 16 chain-groups
#define STH 144          // state row stride in halves (288 B, 16B-aligned)

// ws layout (bytes)
#define LENS_OFF 256
#define AF_OFF 2048
#define CF_OFF (AF_OFF + BB * NN * 4)
#define BU_OFF (CF_OFF + 1024)
#define CB_OFF (BU_OFF + BB * NN * 4)
#define XQ_OFF (CB_OFF + 1024)
#define XQ_SZ ((size_t)TT * BB * NN * 2)

typedef __attribute__((ext_vector_type(8))) short short8_t;
typedef __attribute__((ext_vector_type(4))) float f32x4;

__device__ __forceinline__ unsigned short f2bf(float f) {
  unsigned u = __float_as_uint(f);
  return (unsigned short)((u + 0x7FFF + ((u >> 16) & 1)) >> 16);  // RNE
}
__device__ __forceinline__ float bf2f(unsigned short h) {
  return __uint_as_float(((unsigned)h) << 16);
}
// storage position p <-> original index:  idx = 32w+16u+c  <->  p = 32w+2c+u
__device__ __forceinline__ int orig_j(int p) {
  return 32 * (p >> 5) + 16 * (p & 1) + ((p >> 1) & 15);
}
// packed RNE f32->bf16 pair (lo=a, hi=b) — single VALU op
__device__ __forceinline__ unsigned pk_bf16(float a, float b) {
  unsigned r;
  asm("v_cvt_pk_bf16_f32 %0, %1, %2" : "=v"(r) : "v"(a), "v"(b));
  return r;
}

// lgkmcnt-only barrier: LDS producer/consumer ordering without draining
// outstanding global (Xq prefetch) loads.  "memory" clobber pins all
// memory ops on either side; compiler still inserts counted vmcnt waits
// before each xq[k] register use.
#define BARRIER_LGKM() \
  asm volatile("s_waitcnt lgkmcnt(0)\n\ts_barrier" ::: "memory")

// ---------- Phase 1: fused exp(emit)->Xq staging + gold score --------------
// Blocks [0, NWG*TT): expemit body.  Blocks [NWG*TT, NWG*TT+TT): score body.
__global__ __launch_bounds__(256) void crf_pre(
    const float* __restrict__ emit, const int* __restrict__ target,
    const void* __restrict__ maskp, const float* __restrict__ trans,
    const float* __restrict__ strans, const float* __restrict__ etrans,
    uint4* __restrict__ Xq, float* __restrict__ ws, int* __restrict__ lens) {
  __shared__ float rf[4];
  const int bid = blockIdx.x;
  if (bid < NWG * TT) {
    // ---- expemit ----
    const int g = bid >> 9;
    const int t = bid & (TT - 1);
    const int tid = threadIdx.x;
    const int w = tid >> 6, l = tid & 63, qd = l >> 4, c = l & 15;
    const int bg = g * MW;
    unsigned pk[4];
#pragma unroll
    for (int r = 0; r < 4; ++r) {
      const size_t row = ((size_t)t * BB + bg + 4 * qd + r) * NN + 32 * w + c;
      float v0 = __expf(emit[row]);
      float v1 = __expf(emit[row + 16]);
      pk[r] = (unsigned)f2bf(v0) | ((unsigned)f2bf(v1) << 16);
    }
    Xq[((size_t)g * TT + t) * 256 + tid] =
        make_uint4(pk[0], pk[1], pk[2], pk[3]);
  } else {
    // ---- score ----
    const int b = threadIdx.x;
    const int t = bid - NWG * TT;
    const unsigned char* mk8 = (const unsigned char*)maskp;
    const int* mk32 = (const int*)maskp;
    const bool is_u8 = (mk8[1] != 0);

    int m = is_u8 ? (mk8[t * BB + b] != 0) : (mk32[t * BB + b] != 0);
    float v = 0.f;
    if (m) {
      int tg = target[t * BB + b];
      v = emit[((size_t)t * BB + b) * NN + tg];
      v += (t > 0) ? trans[target[(t - 1) * BB + b] * NN + tg] : strans[tg];
      int mn = (t + 1 < TT) ? (is_u8 ? (mk8[(t + 1) * BB + b] != 0)
                                     : (mk32[(t + 1) * BB + b] != 0))
                            : 0;
      if (!mn) {  // prefix-mask edge = last valid step
        v += etrans[tg];
        lens[b] = t + 1;
      }
    }
#pragma unroll
    for (int off = 32; off; off >>= 1) v += __shfl_down(v, off, 64);
    if ((b & 63) == 0) rf[b >> 6] = v;
    __syncthreads();
    if (b == 0) atomicAdd(&ws[1], rf[0] + rf[1] + rf[2] + rf[3]);
  }
}

// ---------- Phase 2: fwd (blocks 0..15) + bwd (blocks 16..31) recursions ---
// R0 structure (verified) + three critical-path cuts:
//  (a) lgkmcnt-only barrier (Xq prefetch stays in flight across steps)
//  (b) v_cvt_pk_bf16_f32 packing
//  (c) renorm every 2nd step (scaling is exact bookkeeping; growth <=2^14/step
//      keeps peaks ~2^24, comb dot <=2^56 — f32-safe)
__global__ __launch_bounds__(256, 1) void crf_fb3(
    const float* __restrict__ emit, const float* __restrict__ trans,
    const float* __restrict__ strans, const float* __restrict__ etrans,
    const uint4* __restrict__ Xq, const int* __restrict__ lens,
    float* __restrict__ AF, int* __restrict__ CF,
    float* __restrict__ BU, int* __restrict__ CB) {
  __shared__ __align__(16) unsigned short sV[2][MW * STH];
  __shared__ __align__(16) int nrm[2][MW];
  __shared__ __align__(16) int sC[MW];
  __shared__ int slen[MW];
  __shared__ int smax_s;

  const int tid = threadIdx.x;
  const int w = tid >> 6;
  const int l = tid & 63;
  const int c = l & 15;
  const int qd = l >> 4;
  const bool bwd = (blockIdx.x >= NWG);
  const int g = bwd ? (int)blockIdx.x - NWG : (int)blockIdx.x;
  const int bg = g * MW;

  if (tid == 0) smax_s = 0;
  if (tid < MW) slen[tid] = lens[bg + tid];
  __syncthreads();
  if (tid < MW) atomicMax(&smax_s, slen[tid]);

  // ---- E fragments (bwd: transposed orientation) ----
  short8_t eB[4][2];
#pragma unroll
  for (int kt = 0; kt < 4; ++kt)
#pragma unroll
    for (int u = 0; u < 2; ++u)
#pragma unroll
      for (int jj = 0; jj < 8; ++jj) {
        int kp = kt * 32 + qd * 8 + jj;
        int a_ = orig_j(kp);
        int b_ = 32 * w + 16 * u + c;
        float tv = bwd ? trans[b_ * NN + a_] : trans[a_ * NN + b_];
        eB[kt][u][jj] = (short)f2bf(__expf(tv));
      }
  const float eet0 = __expf(etrans[32 * w + c]);
  const float eet1 = __expf(etrans[32 * w + 16 + c]);

  // ---- init state ----
  {
    const int m = tid & 15;
    const int pbase = (tid >> 4) * 8;
    if (!bwd) {
      const int b = bg + m;
#pragma unroll
      for (int pp = 0; pp < 8; ++pp) {
        int p = pbase + pp;
        int j = orig_j(p);
        float v = __expf(strans[j] + emit[(size_t)b * NN + j]);
        sV[0][m * STH + p] = f2bf(v);
        if (p == 0)
          nrm[0][m] = ((int)((__float_as_uint(v) >> 23) & 0xFF)) - 120;
      }
    } else {
#pragma unroll
      for (int pp = 0; pp < 8; ++pp) {
        int p = pbase + pp;
        sV[0][m * STH + p] = 0x3F80;  // 1.0 bf16
        sV[1][m * STH + p] = 0x3F80;
        if (p == 0) { nrm[0][m] = 0; nrm[1][m] = 0; }
      }
    }
  }
  __syncthreads();
  const int smax = smax_s;
  int lm1[4];
#pragma unroll
  for (int r = 0; r < 4; ++r) lm1[r] = slen[4 * qd + r] - 1;

  int cloc[4] = {0, 0, 0, 0};
  int nb = 0;  // nrm ping-pong (toggles at norm steps only; uniform)
  const bool nwriter = (w == 0 && c == 0);
  const uint4* Xg = Xq + (size_t)g * TT * 256 + tid;

#define FB_MFMA()                                                             \
    const short8_t A0 = *(const short8_t*)&sV[PIN][c * STH + 0 + qd * 8];     \
    const short8_t A1 = *(const short8_t*)&sV[PIN][c * STH + 32 + qd * 8];    \
    const short8_t A2 = *(const short8_t*)&sV[PIN][c * STH + 64 + qd * 8];    \
    const short8_t A3 = *(const short8_t*)&sV[PIN][c * STH + 96 + qd * 8];    \
    f32x4 p0 = {0.f, 0.f, 0.f, 0.f}, q0 = {0.f, 0.f, 0.f, 0.f};              \
    f32x4 p1 = {0.f, 0.f, 0.f, 0.f}, q1 = {0.f, 0.f, 0.f, 0.f};              \
    p0 = __builtin_amdgcn_mfma_f32_16x16x32_bf16(A0, eB[0][0], p0, 0, 0, 0); \
    p1 = __builtin_amdgcn_mfma_f32_16x16x32_bf16(A0, eB[0][1], p1, 0, 0, 0); \
    q0 = __builtin_amdgcn_mfma_f32_16x16x32_bf16(A2, eB[2][0], q0, 0, 0, 0); \
    q1 = __builtin_amdgcn_mfma_f32_16x16x32_bf16(A2, eB[2][1], q1, 0, 0, 0); \
    p0 = __builtin_amdgcn_mfma_f32_16x16x32_bf16(A1, eB[1][0], p0, 0, 0, 0); \
    p1 = __builtin_amdgcn_mfma_f32_16x16x32_bf16(A1, eB[1][1], p1, 0, 0, 0); \
    q0 = __builtin_amdgcn_mfma_f32_16x16x32_bf16(A3, eB[3][0], q0, 0, 0, 0); \
    q1 = __builtin_amdgcn_mfma_f32_16x16x32_bf16(A3, eB[3][1], q1, 0, 0, 0); \
    const f32x4 ac0 = p0 + q0;                                                \
    const f32x4 ac1 = p1 + q1;

  if (!bwd) {
    const int LmaxF = (smax < 258) ? smax : 258;  // steps t <= 257
    for (int tb = 1; tb < LmaxF; tb += 8) {
      uint4 xq[8];
#pragma unroll
      for (int k = 0; k < 8; ++k) {
        int t = tb + k;
        if (t > TT - 1) t = TT - 1;
        xq[k] = Xg[(size_t)t * 256];
      }
#pragma unroll
      for (int k = 0; k < 8; ++k) {
        const int T_ = tb + k;
        if (T_ >= LmaxF) break;
        const int POUT = T_ & 1, PIN = POUT ^ 1;
        const bool NORM = (k & 1) != 0;  // renorm cadence 2
        FB_MFMA();
        const unsigned xd[4] = {xq[k].x, xq[k].y, xq[k].z, xq[k].w};
        if (NORM) {
          const int4 nr = *(const int4*)&nrm[nb][4 * qd];
          const int nA[4] = {nr.x, nr.y, nr.z, nr.w};
          int nnw[4];
#pragma unroll
          for (int r_ = 0; r_ < 4; ++r_) {
            float x0 = __uint_as_float(xd[r_] << 16);
            float x1 = __uint_as_float(xd[r_] & 0xffff0000u);
            float v0 = ldexpf(ac0[r_] * x0, -nA[r_]);
            float v1 = ldexpf(ac1[r_] * x1, -nA[r_]);
            if (T_ <= lm1[r_]) {
              *(unsigned*)&sV[POUT][(4 * qd + r_) * STH + 32 * w + 2 * c] =
                  pk_bf16(v0, v1);
              cloc[r_] += nA[r_];
            }
            nnw[r_] = ((int)((__float_as_uint(v0) >> 23) & 0xFF)) - 120;
          }
          if (nwriter)
            *(int4*)&nrm[nb ^ 1][4 * qd] =
                make_int4(nnw[0], nnw[1], nnw[2], nnw[3]);
          nb ^= 1;
        } else {
#pragma unroll
          for (int r_ = 0; r_ < 4; ++r_) {
            float x0 = __uint_as_float(xd[r_] << 16);
            float x1 = __uint_as_float(xd[r_] & 0xffff0000u);
            float v0 = ac0[r_] * x0;
            float v1 = ac1[r_] * x1;
            if (T_ <= lm1[r_]) {
              *(unsigned*)&sV[POUT][(4 * qd + r_) * STH + 32 * w + 2 * c] =
                  pk_bf16(v0, v1);
            }
          }
        }
        BARRIER_LGKM();
      }
    }
  } else if (smax >= 259) {
    for (int tb = smax - 1; tb >= 258; tb -= 8) {
      uint4 xq[8];
#pragma unroll
      for (int k = 0; k < 8; ++k) {
        int t = tb - k;
        if (t < 258) t = 258;
        xq[k] = Xg[(size_t)t * 256];
      }
#pragma unroll
      for (int k = 0; k < 8; ++k) {
        const int T_ = tb - k;
        if (T_ < 258) break;
        const int POUT = T_ & 1, PIN = POUT ^ 1;
        const bool NORM = (k & 1) != 0;
        FB_MFMA();
        const unsigned xd[4] = {xq[k].x, xq[k].y, xq[k].z, xq[k].w};
        if (NORM) {
          const int4 nr = *(const int4*)&nrm[nb][4 * qd];
          const int nA[4] = {nr.x, nr.y, nr.z, nr.w};
          int nnw[4];
#pragma unroll
          for (int r_ = 0; r_ < 4; ++r_) {
            float x0 = __uint_as_float(xd[r_] << 16);
            float x1 = __uint_as_float(xd[r_] & 0xffff0000u);
            const bool isact = (T_ == lm1[r_]);
            float v0 = isact ? x0 * eet0 : ldexpf(ac0[r_] * x0, -nA[r_]);
            float v1 = isact ? x1 * eet1 : ldexpf(ac1[r_] * x1, -nA[r_]);
            if (T_ <= lm1[r_]) {
              *(unsigned*)&sV[POUT][(4 * qd + r_) * STH + 32 * w + 2 * c] =
                  pk_bf16(v0, v1);
              cloc[r_] = isact ? 0 : cloc[r_] + nA[r_];
            }
            nnw[r_] = ((int)((__float_as_uint(v0) >> 23) & 0xFF)) - 120;
          }
          if (nwriter)
            *(int4*)&nrm[nb ^ 1][4 * qd] =
                make_int4(nnw[0], nnw[1], nnw[2], nnw[3]);
          nb ^= 1;
        } else {
#pragma unroll
          for (int r_ = 0; r_ < 4; ++r_) {
            float x0 = __uint_as_float(xd[r_] << 16);
            float x1 = __uint_as_float(xd[r_] & 0xffff0000u);
            const bool isact = (T_ == lm1[r_]);
            float v0 = isact ? x0 * eet0 : ac0[r_] * x0;
            float v1 = isact ? x1 * eet1 : ac1[r_] * x1;
            if (T_ <= lm1[r_]) {
              *(unsigned*)&sV[POUT][(4 * qd + r_) * STH + 32 * w + 2 * c] =
                  pk_bf16(v0, v1);
              cloc[r_] = isact ? 0 : cloc[r_];
            }
          }
        }
        BARRIER_LGKM();
      }
    }
  }
#undef FB_MFMA

  // ---- epilogue: dump per-chain state + pow2 counters to global ----
  if (nwriter)
    *(int4*)&sC[4 * qd] = make_int4(cloc[0], cloc[1], cloc[2], cloc[3]);
  __syncthreads();
  {
    const int m = tid >> 4, i16 = tid & 15;
    if (!bwd) {
      int nf = slen[m] - 1;
      if (nf > 257) nf = 257;
      const int pf = nf & 1;
#pragma unroll
      for (int pp = 0; pp < 8; ++pp) {
        int p = i16 * 8 + pp;
        AF[(size_t)(bg + m) * NN + p] = bf2f(sV[pf][m * STH + p]);
      }
      if (i16 == 0) CF[bg + m] = sC[m];
    } else {
      // active chains all end at t=258 -> parity 0; inactive: init (unused)
#pragma unroll
      for (int pp = 0; pp < 8; ++pp) {
        int p = i16 * 8 + pp;
        BU[(size_t)(bg + m) * NN + p] = bf2f(sV[0][m * STH + p]);
      }
      if (i16 == 0) CB[bg + m] = sC[m];
    }
  }
}

// ---------- Phase 3: combine.  logZ_b = ln2*(CF+CB) + ln(alpha_257 . E U_258)
// (len>=259) or ln2*CF + ln(alpha . exp(etrans)) (len<=258). ----------------
__global__ __launch_bounds__(256) void crf_comb(
    const float* __restrict__ trans, const float* __restrict__ etrans,
    const int* __restrict__ lens, const float* __restrict__ AF,
    const int* __restrict__ CF, const float* __restrict__ BU,
    const int* __restrict__ CB, float* __restrict__ ws,
    float* __restrict__ out) {
  __shared__ __align__(16) unsigned short sU[MW * STH];
  __shared__ float sRed[4][MW][2];
  __shared__ int slen[MW];
  const int tid = threadIdx.x;
  const int w = tid >> 6, l = tid & 63, c = l & 15, qd = l >> 4;
  const int g = blockIdx.x, bg = g * MW;

  if (tid < MW) slen[tid] = lens[bg + tid];
  {
    const int m = tid & 15, pbase = (tid >> 4) * 8;
#pragma unroll
    for (int pp = 0; pp < 8; ++pp) {
      int p = pbase + pp;
      sU[m * STH + p] = f2bf(BU[(size_t)(bg + m) * NN + p]);
    }
  }
  short8_t eB[4][2];
#pragma unroll
  for (int kt = 0; kt < 4; ++kt)
#pragma unroll
    for (int u = 0; u < 2; ++u)
#pragma unroll
      for (int jj = 0; jj < 8; ++jj) {
        int kp = kt * 32 + qd * 8 + jj;
        int a_ = orig_j(kp);
        int b_ = 32 * w + 16 * u + c;
        eB[kt][u][jj] = (short)f2bf(__expf(trans[b_ * NN + a_]));  // bwd orient
      }
  const float eet0 = __expf(etrans[32 * w + c]);
  const float eet1 = __expf(etrans[32 * w + 16 + c]);
  __syncthreads();

  const short8_t A0 = *(const short8_t*)&sU[c * STH + 0 + qd * 8];
  const short8_t A1 = *(const short8_t*)&sU[c * STH + 32 + qd * 8];
  const short8_t A2 = *(const short8_t*)&sU[c * STH + 64 + qd * 8];
  const short8_t A3 = *(const short8_t*)&sU[c * STH + 96 + qd * 8];
  f32x4 ac0 = {0.f, 0.f, 0.f, 0.f}, ac1 = {0.f, 0.f, 0.f, 0.f};
  ac0 = __builtin_amdgcn_mfma_f32_16x16x32_bf16(A0, eB[0][0], ac0, 0, 0, 0);
  ac1 = __builtin_amdgcn_mfma_f32_16x16x32_bf16(A0, eB[0][1], ac1, 0, 0, 0);
  ac0 = __builtin_amdgcn_mfma_f32_16x16x32_bf16(A1, eB[1][0], ac0, 0, 0, 0);
  ac1 = __builtin_amdgcn_mfma_f32_16x16x32_bf16(A1, eB[1][1], ac1, 0, 0, 0);
  ac0 = __builtin_amdgcn_mfma_f32_16x16x32_bf16(A2, eB[2][0], ac0, 0, 0, 0);
  ac1 = __builtin_amdgcn_mfma_f32_16x16x32_bf16(A2, eB[2][1], ac1, 0, 0, 0);
  ac0 = __builtin_amdgcn_mfma_f32_16x16x32_bf16(A3, eB[3][0], ac0, 0, 0, 0);
  ac1 = __builtin_amdgcn_mfma_f32_16x16x32_bf16(A3, eB[3][1], ac1, 0, 0, 0);

#pragma unroll
  for (int r_ = 0; r_ < 4; ++r_) {
    // alpha at cols i0 = 32w+c (p=32w+2c), i1 = 32w+16+c (p=32w+2c+1)
    float a0 = AF[(size_t)(bg + 4 * qd + r_) * NN + 32 * w + 2 * c];
    float a1 = AF[(size_t)(bg + 4 * qd + r_) * NN + 32 * w + 2 * c + 1];
    float dB = a0 * ac0[r_] + a1 * ac1[r_];
    float dA = a0 * eet0 + a1 * eet1;
#pragma unroll
    for (int mk = 1; mk < 16; mk <<= 1) {
      dB += __shfl_xor(dB, mk, 64);
      dA += __shfl_xor(dA, mk, 64);
    }
    if (c == 0) {
      sRed[w][4 * qd + r_][0] = dB;
      sRed[w][4 * qd + r_][1] = dA;
    }
  }
  __syncthreads();
  if (tid < MW) {
    float DB = sRed[0][tid][0] + sRed[1][tid][0] + sRed[2][tid][0] + sRed[3][tid][0];
    float DA = sRed[0][tid][1] + sRed[1][tid][1] + sRed[2][tid][1] + sRed[3][tid][1];
    const int len = slen[tid];
    const float LN2 = 0.6931471805599453f;
    float logZ;
    if (len >= 259)
      logZ = LN2 * (float)(CF[bg + tid] + CB[bg + tid]) + __logf(DB);
    else
      logZ = LN2 * (float)CF[bg + tid] + __logf(DA);
    atomicAdd(&ws[0], logZ);
  }
  __syncthreads();
  if (tid == 0) {
    __threadfence();
    unsigned old = atomicAdd((unsigned*)ws + 3, 1u);
    if (old == NWG - 1) {
      float zz = atomicAdd(&ws[0], 0.f);
      float ss = atomicAdd(&ws[1], 0.f);
      out[0] = (zz - ss) * (1.0f / (float)BB);
    }
  }
}

// ---------- Fallback (Round-5 fused kernel, verified) ----------------------
__global__ __launch_bounds__(256, 1) void crf_fused_fb(
    const float* __restrict__ emit, const int* __restrict__ target,
    const void* __restrict__ maskp, const float* __restrict__ trans,
    const float* __restrict__ strans, const float* __restrict__ etrans,
    float* __restrict__ ws, float* __restrict__ out) {
  __shared__ __align__(16) unsigned short sV[2][MW * STH];
  __shared__ __align__(16) int nrm[2][MW];
  __shared__ __align__(16) int sC[MW];
  __shared__ int slen[MW];
  __shared__ float sscore;
  __shared__ int smax;

  const int tid = threadIdx.x;
  const int w = tid >> 6;
  const int l = tid & 63;
  const int c = l & 15;
  const int qd = l >> 4;
  const int bg = blockIdx.x * MW;

  if (tid < MW) slen[tid] = 0;
  if (tid == 0) { sscore = 0.f; smax = 0; }
  __syncthreads();

  const unsigned char* mk8 = (const unsigned char*)maskp;
  const int* mk32 = (const int*)maskp;
  const bool is_u8 = (mk8[1] != 0);
  {
    const int mi = tid & 15;
    const int b = bg + mi;
    const int t0 = (tid >> 4) * 32;
    int cnt = 0;
    float sc = 0.f;
    for (int s = 0; s < 32; ++s) {
      int t = t0 + s;
      int m = is_u8 ? (mk8[t * BB + b] != 0) : (mk32[t * BB + b] != 0);
      if (m) {
        cnt++;
        int tg = target[t * BB + b];
        float v = emit[((size_t)t * BB + b) * NN + tg];
        v += (t > 0) ? trans[target[(t - 1) * BB + b] * NN + tg] : strans[tg];
        int mn = (t + 1 < TT) ? (is_u8 ? (mk8[(t + 1) * BB + b] != 0)
                                       : (mk32[(t + 1) * BB + b] != 0))
                              : 0;
        if (!mn) v += etrans[tg];
        sc += v;
      }
    }
    atomicAdd(&slen[mi], cnt);
    atomicAdd(&sscore, sc);
  }

  short8_t eB[4][2];
#pragma unroll
  for (int kt = 0; kt < 4; ++kt)
#pragma unroll
    for (int u = 0; u < 2; ++u)
#pragma unroll
      for (int jj = 0; jj < 8; ++jj) {
        int kp = kt * 32 + qd * 8 + jj;
        int i = orig_j(kp);
        int j = 32 * w + 16 * u + c;
        eB[kt][u][jj] = (short)f2bf(__expf(trans[i * NN + j]));
      }

  {
    const int m = tid & 15;
    const int b = bg + m;
    const int pbase = (tid >> 4) * 8;
#pragma unroll
    for (int pp = 0; pp < 8; ++pp) {
      int p = pbase + pp;
      int j = orig_j(p);
      float v = __expf(strans[j] + emit[(size_t)b * NN + j]);
      sV[0][m * STH + p] = f2bf(v);
      if (p == 0)
        nrm[0][m] = ((int)((__float_as_uint(v) >> 23) & 0xFF)) - 120;
    }
  }
  __syncthreads();

  if (tid < MW) atomicMax(&smax, slen[tid]);
  if (tid == 0) atomicAdd(&ws[1], sscore);
  __syncthreads();
  const int Lmax = smax;
  int lenr[4];
#pragma unroll
  for (int r = 0; r < 4; ++r) lenr[r] = slen[4 * qd + r];

  int off8[8];
#pragma unroll
  for (int r = 0; r < 4; ++r)
#pragma unroll
    for (int u = 0; u < 2; ++u)
      off8[r * 2 + u] = (bg + 4 * qd + r) * NN + 32 * w + 16 * u + c;

  float ra[8], rb[8], xv[8];
  {
#pragma unroll
    for (int i = 0; i < 8; ++i) ra[i] = emit[(size_t)1 * BB * NN + off8[i]];
#pragma unroll
    for (int i = 0; i < 8; ++i) rb[i] = emit[(size_t)2 * BB * NN + off8[i]];
#pragma unroll
    for (int i = 0; i < 8; ++i) xv[i] = __expf(ra[i]);
  }
  int cloc[4] = {0, 0, 0, 0};
  const bool nwriter = (w == 0 && c == 0);

#define CRF_STEP(T_, PIN, POUT, RL, RO)                                       \
  do {                                                                        \
    int tl = ((T_) + 2 < TT) ? (T_) + 2 : TT - 1;                             \
    const size_t gbase = (size_t)tl * (BB * NN);                              \
    _Pragma("unroll") for (int i_ = 0; i_ < 8; ++i_)                          \
        RL[i_] = emit[gbase + off8[i_]];                                      \
    const short8_t A0 = *(const short8_t*)&sV[PIN][c * STH + 0 + qd * 8];     \
    const short8_t A1 = *(const short8_t*)&sV[PIN][c * STH + 32 + qd * 8];    \
    const short8_t A2 = *(const short8_t*)&sV[PIN][c * STH + 64 + qd * 8];    \
    const short8_t A3 = *(const short8_t*)&sV[PIN][c * STH + 96 + qd * 8];    \
    const int4 nr = *(const int4*)&nrm[PIN][4 * qd];                          \
    f32x4 ac0 = {0.f, 0.f, 0.f, 0.f}, ac1 = {0.f, 0.f, 0.f, 0.f};             \
    ac0 = __builtin_amdgcn_mfma_f32_16x16x32_bf16(A0, eB[0][0], ac0, 0, 0, 0);\
    ac1 = __builtin_amdgcn_mfma_f32_16x16x32_bf16(A0, eB[0][1], ac1, 0, 0, 0);\
    ac0 = __builtin_amdgcn_mfma_f32_16x16x32_bf16(A1, eB[1][0], ac0, 0, 0, 0);\
    ac1 = __builtin_amdgcn_mfma_f32_16x16x32_bf16(A1, eB[1][1], ac1, 0, 0, 0);\
    ac0 = __builtin_amdgcn_mfma_f32_16x16x32_bf16(A2, eB[2][0], ac0, 0, 0, 0);\
    ac1 = __builtin_amdgcn_mfma_f32_16x16x32_bf16(A2, eB[2][1], ac1, 0, 0, 0);\
    ac0 = __builtin_amdgcn_mfma_f32_16x16x32_bf16(A3, eB[3][0], ac0, 0, 0, 0);\
    ac1 = __builtin_amdgcn_mfma_f32_16x16x32_bf16(A3, eB[3][1], ac1, 0, 0, 0);\
    const int nA[4] = {nr.x, nr.y, nr.z, nr.w};                               \
    int nnw[4];                                                               \
    _Pragma("unroll") for (int r_ = 0; r_ < 4; ++r_) {                        \
      float y0 = ac0[r_] * xv[2 * r_];                                        \
      float y1 = ac1[r_] * xv[2 * r_ + 1];                                    \
      float v0 = ldexpf(y0, -nA[r_]);                                         \
      float v1 = ldexpf(y1, -nA[r_]);                                         \
      if ((T_) < lenr[r_]) {                                                  \
        unsigned pk = (unsigned)f2bf(v0) | ((unsigned)f2bf(v1) << 16);        \
        *(unsigned*)&sV[POUT][(4 * qd + r_) * STH + 32 * w + 2 * c] = pk;     \
        cloc[r_] += nA[r_];                                                   \
      }                                                                       \
      nnw[r_] = ((int)((__float_as_uint(v0) >> 23) & 0xFF)) - 120;            \
    }                                                                         \
    if (nwriter)                                                              \
      *(int4*)&nrm[POUT][4 * qd] = make_int4(nnw[0], nnw[1], nnw[2], nnw[3]); \
    _Pragma("unroll") for (int i_ = 0; i_ < 8; ++i_)                          \
        xv[i_] = __expf(RO[i_]);                                              \
    __syncthreads();                                                          \
  } while (0)

  for (int t = 1; t < Lmax; t += 2) {
    CRF_STEP(t, 0, 1, ra, rb);
    if (t + 1 < Lmax) {
      CRF_STEP(t + 1, 1, 0, rb, ra);
    }
  }
#undef CRF_STEP

  if (nwriter) *(int4*)&sC[4 * qd] = make_int4(cloc[0], cloc[1], cloc[2], cloc[3]);
  __syncthreads();
  {
    const int m = tid >> 4, i16 = tid & 15;
    const int pb = (slen[m] - 1) & 1;
    float s = 0.f;
#pragma unroll
    for (int pp = 0; pp < 8; ++pp) {
      int p = i16 * 8 + pp;
      int j = orig_j(p);
      s += bf2f(sV[pb][m * STH + p]) * __expf(etrans[j]);
    }
    s += __shfl_xor(s, 1, 64);
    s += __shfl_xor(s, 2, 64);
    s += __shfl_xor(s, 4, 64);
    s += __shfl_xor(s, 8, 64);
    if (i16 == 0)
      atomicAdd(&ws[0], (float)sC[m] * 0.69314718f + __logf(s));
  }
  __syncthreads();
  if (tid == 0) {
    __threadfence();
    unsigned old = atomicAdd((unsigned*)ws + 3, 1u);
    if (old == NWG - 1) {
      float zz = atomicAdd(&ws[0], 0.f);
      float ss = atomicAdd(&ws[1], 0.f);
      out[0] = (zz - ss) * (1.0f / (float)BB);
    }
  }
}

extern "C" void kernel_launch(void* const* d_in, const int* in_sizes, int n_in,
                              void* d_out, int out_size, void* d_ws, size_t ws_size,
                              hipStream_t stream) {
  const float* emit = (const float*)d_in[0];
  const int* target = (const int*)d_in[1];
  const void* mask = (const void*)d_in[2];
  const float* trans = (const float*)d_in[3];
  const float* strans = (const float*)d_in[4];
  const float* etrans = (const float*)d_in[5];
  float* ws = (float*)d_ws;
  float* out = (float*)d_out;

  const size_t need = (size_t)XQ_OFF + XQ_SZ;
  hipMemsetAsync(d_ws, 0, 16, stream);
  if (ws_size >= need) {
    int* lens = (int*)((char*)d_ws + LENS_OFF);
    float* AF = (float*)((char*)d_ws + AF_OFF);
    int* CF = (int*)((char*)d_ws + CF_OFF);
    float* BU = (float*)((char*)d_ws + BU_OFF);
    int* CB = (int*)((char*)d_ws + CB_OFF);
    uint4* Xq = (uint4*)((char*)d_ws + XQ_OFF);
    crf_pre<<<NWG * TT + TT, 256, 0, stream>>>(emit, target, mask, trans,
                                               strans, etrans, Xq, ws, lens);
    crf_fb3<<<2 * NWG, 256, 0, stream>>>(emit, trans, strans, etrans,
                                         (const uint4*)Xq, lens, AF, CF, BU,
                                         CB);
    crf_comb<<<NWG, 256, 0, stream>>>(trans, etrans, lens, AF, CF, BU, CB, ws,
                                      out);
  } else {
    crf_fused_fb<<<NWG, 256, 0, stream>>>(emit, target, mask, trans, strans,
                                          etrans, ws, out);
  }
}